// Round 3
// baseline (36.619 us; speedup 1.0000x reference)
//
#include <hip/hip_runtime.h>
#include <math.h>

#define BATCH 8
#define G 256
#define A_TOT 32256
#define NBLK 126            // A_TOT / 256
#define GRID_BLKS (BATCH * NBLK)

// LO/HI bands per level: computed in double, truncated to f32 (matches np.float32(a*RATE))
__constant__ float c_LO[6] = {
    0.0f,
    (float)(0.32537674 * (22050.0 / 256.0)),
    (float)(0.47555801 * (22050.0 / 256.0)),
    (float)(0.64588683 * (22050.0 / 256.0)),
    (float)(1.16883525 * (22050.0 / 256.0)),
    (float)(2.17128976 * (22050.0 / 256.0)),
};
__constant__ float c_HI[6] = {
    (float)(0.32537674 * (22050.0 / 256.0)),
    (float)(0.47555801 * (22050.0 / 256.0)),
    (float)(0.64588683 * (22050.0 / 256.0)),
    (float)(1.16883525 * (22050.0 / 256.0)),
    (float)(2.17128976 * (22050.0 / 256.0)),
    INFINITY,
};

// Single fused kernel:
//  - per-block replicated stable length-sort (O(G^2) rank count, float4 LDS reads)
//  - per-level candidate range [jlo,jhi) via binary search (len in [LO, 2*HI) is
//    necessary for any match; 0.01 margin covers fp32 rounding; widening the
//    range is always safe because the match predicate itself is exact)
//  - branchless min-index first-match scan, 2 annotations per float4 LDS read
//  - GIoU for positives, shfl wave reduce, per-block partial store
//  - last block per sample (agent-scope counter) reduces 126 partials in a
//    fixed tree order -> bit-deterministic output, no float atomics
__global__ __launch_bounds__(256) void fcos_fused_kernel(
    const float* __restrict__ reg,      // (B, A_TOT, 2)
    const float* __restrict__ ann,      // (B, G, 3)
    float* __restrict__ pLoss,          // (B, NBLK)
    float* __restrict__ pCnt,           // (B, NBLK)
    int* __restrict__ done,             // (B,)  zeroed before launch
    float* __restrict__ out)            // (B,)
{
    const int bid = blockIdx.x;
    const int b   = bid / NBLK;
    const int blk = bid % NBLK;
    const int t   = threadIdx.x;

    __shared__ float  s_len[G];
    __shared__ float  s_slen[G];
    __shared__ float2 s_ann[G];
    __shared__ float  s_wl[4], s_wc[4];
    __shared__ int    s_last;

    // ---- load + stable rank-sort by length ----
    const float a0in = ann[(b * G + t) * 3 + 0];
    const float a1in = ann[(b * G + t) * 3 + 1];
    const float myLen = a1in - a0in;
    s_len[t] = myLen;
    __syncthreads();

    int rank = 0;
    const float4* s_len4 = reinterpret_cast<const float4*>(s_len);
#pragma unroll 8
    for (int k4 = 0; k4 < G / 4; ++k4) {
        const float4 v = s_len4[k4];
        const int k = k4 * 4;
        rank += (v.x < myLen) || (v.x == myLen && (k + 0) < t);
        rank += (v.y < myLen) || (v.y == myLen && (k + 1) < t);
        rank += (v.z < myLen) || (v.z == myLen && (k + 2) < t);
        rank += (v.w < myLen) || (v.w == myLen && (k + 3) < t);
    }
    s_ann[rank]  = make_float2(a0in, a1in);
    s_slen[rank] = myLen;
    __syncthreads();

    // ---- level of this block (boundaries are multiples of 256) ----
    const int aidx0 = blk * 256;
    int lvl, off;
    if (aidx0 < 16384)      { lvl = 0; off = 0; }
    else if (aidx0 < 24576) { lvl = 1; off = 16384; }
    else if (aidx0 < 28672) { lvl = 2; off = 24576; }
    else if (aidx0 < 30720) { lvl = 3; off = 28672; }
    else if (aidx0 < 31744) { lvl = 4; off = 30720; }
    else                    { lvl = 5; off = 31744; }

    const int   aidx = aidx0 + t;
    const float p    = (float)(aidx - off) * (float)(1 << lvl);  // exact
    const float lo   = c_LO[lvl];
    const float hi   = c_HI[lvl];

    // ---- candidate range (uniform across block; broadcast LDS binary search) ----
    const float xlo = lo - 0.01f;
    const float xhi = 2.0f * hi + 0.01f;   // inf stays inf
    int l0 = 0, h0 = G;
    while (l0 < h0) { const int mid = (l0 + h0) >> 1; if (s_slen[mid] < xlo) l0 = mid + 1; else h0 = mid; }
    int l1 = l0, h1 = G;
    while (l1 < h1) { const int mid = (l1 + h1) >> 1; if (s_slen[mid] < xhi) l1 = mid + 1; else h1 = mid; }
    const int jlo = l0 & ~1;                    // widen to even (safe)
    int jhi = (l1 + 1) & ~1; if (jhi > G) jhi = G;

    // ---- branchless min-index first-match scan, 2 anns per iteration ----
    int bestJ = 0x7FFFFFFF;
    const float4* s_ann4 = reinterpret_cast<const float4*>(s_ann);
#pragma unroll 4
    for (int j2 = jlo >> 1; j2 < (jhi >> 1); ++j2) {
        const float4 v = s_ann4[j2];
        const float la = p - v.x, ra = v.y - p;
        const float lb = p - v.z, rb2 = v.w - p;
        const float ma = fmaxf(la, ra), mb = fmaxf(lb, rb2);
        if (fminf(lb, rb2) >= 0.f && mb >= lo && mb < hi) bestJ = min(bestJ, 2 * j2 + 1);
        if (fminf(la, ra)  >= 0.f && ma >= lo && ma < hi) bestJ = min(bestJ, 2 * j2);
    }

    // ---- GIoU for positives ----
    float loss = 0.f, cnt = 0.f;
    if (bestJ != 0x7FFFFFFF) {
        const float2 aj = s_ann[bestJ];
        const float scale = 1.0f / (float)(1 << lvl);   // exact pow2
        const float a0 = aj.x * scale;
        const float a1 = aj.y * scale;
        const float2 rv = reinterpret_cast<const float2*>(reg)[b * A_TOT + aidx];
        const float inter = fmaxf(fminf(a1, rv.y) - fmaxf(a0, rv.x), 0.f);
        const float uni   = (a1 - a0) + (rv.y - rv.x) - inter;
        const float enc   = fmaxf(a1, rv.y) - fminf(a0, rv.x);
        const float iou   = inter / (uni + 1e-7f);
        const float giou  = iou - (enc - uni) / (enc + 1e-7f);
        loss = 1.0f - giou;
        cnt  = 1.0f;
    }

    // ---- wave reduce + block partial ----
#pragma unroll
    for (int m = 32; m; m >>= 1) { loss += __shfl_xor(loss, m); cnt += __shfl_xor(cnt, m); }
    const int wid = t >> 6, lane = t & 63;
    if (lane == 0) { s_wl[wid] = loss; s_wc[wid] = cnt; }
    __syncthreads();
    if (t == 0) {
        const float L = s_wl[0] + s_wl[1] + s_wl[2] + s_wl[3];
        const float C = s_wc[0] + s_wc[1] + s_wc[2] + s_wc[3];
        __hip_atomic_store(&pLoss[b * NBLK + blk], L, __ATOMIC_RELAXED, __HIP_MEMORY_SCOPE_AGENT);
        __hip_atomic_store(&pCnt [b * NBLK + blk], C, __ATOMIC_RELAXED, __HIP_MEMORY_SCOPE_AGENT);
        const int old = __hip_atomic_fetch_add(&done[b], 1, __ATOMIC_ACQ_REL, __HIP_MEMORY_SCOPE_AGENT);
        s_last = (old == NBLK - 1);
    }
    __syncthreads();

    // ---- last block per sample: deterministic final reduction ----
    if (s_last) {
        float L = 0.f, C = 0.f;
        if (t < NBLK) {
            L = __hip_atomic_load(&pLoss[b * NBLK + t], __ATOMIC_RELAXED, __HIP_MEMORY_SCOPE_AGENT);
            C = __hip_atomic_load(&pCnt [b * NBLK + t], __ATOMIC_RELAXED, __HIP_MEMORY_SCOPE_AGENT);
        }
#pragma unroll
        for (int m = 32; m; m >>= 1) { L += __shfl_xor(L, m); C += __shfl_xor(C, m); }
        if (lane == 0) { s_wl[wid] = L; s_wc[wid] = C; }
        __syncthreads();
        if (t == 0) {
            const float Ls = s_wl[0] + s_wl[1] + s_wl[2] + s_wl[3];
            const float Cs = s_wc[0] + s_wc[1] + s_wc[2] + s_wc[3];
            out[b] = Ls / fmaxf(Cs, 1.0f);
        }
    }
}

extern "C" void kernel_launch(void* const* d_in, const int* in_sizes, int n_in,
                              void* d_out, int out_size, void* d_ws, size_t ws_size,
                              hipStream_t stream) {
    const float* reg = (const float*)d_in[0];   // (B, A, 2)
    const float* ann = (const float*)d_in[1];   // (B, G, 3)
    float* out = (float*)d_out;                 // (B,)

    float* pLoss = (float*)d_ws;                        // B*NBLK floats
    float* pCnt  = pLoss + BATCH * NBLK;                // B*NBLK floats
    int*   done  = (int*)(pCnt + BATCH * NBLK);         // B ints

    hipMemsetAsync(done, 0, BATCH * sizeof(int), stream);
    fcos_fused_kernel<<<GRID_BLKS, 256, 0, stream>>>(reg, ann, pLoss, pCnt, done, out);
}

// Round 4
// 21.089 us; speedup vs baseline: 1.7364x; 1.7364x over previous
//
#include <hip/hip_runtime.h>
#include <math.h>

#define BATCH 8
#define G 256
#define A_TOT 32256
#define NBLK 126            // A_TOT / 256

// LO/HI bands per level: computed in double, truncated to f32 (matches np.float32(a*RATE))
__constant__ float c_LO[6] = {
    0.0f,
    (float)(0.32537674 * (22050.0 / 256.0)),
    (float)(0.47555801 * (22050.0 / 256.0)),
    (float)(0.64588683 * (22050.0 / 256.0)),
    (float)(1.16883525 * (22050.0 / 256.0)),
    (float)(2.17128976 * (22050.0 / 256.0)),
};
__constant__ float c_HI[6] = {
    (float)(0.32537674 * (22050.0 / 256.0)),
    (float)(0.47555801 * (22050.0 / 256.0)),
    (float)(0.64588683 * (22050.0 / 256.0)),
    (float)(1.16883525 * (22050.0 / 256.0)),
    (float)(2.17128976 * (22050.0 / 256.0)),
    INFINITY,
};

// Main kernel — NO sort needed. "First match in length-sorted (stable) order"
// == match minimizing (len, orig_idx) lexicographically == scan in original
// order keeping strict len < bestLen. Per block:
//   1. O(G) level-band candidacy test + ballot/prefix compaction into LDS
//      (original order preserved). len in [LO-0.01, 2*HI+0.01) is necessary
//      for any match (m=max(l,r) in [len/2, len]); margin covers fp32 rounding;
//      widening is safe since the match predicate itself is exact.
//   2. Branchless scan, 2 candidates/iter (float4 pair + float2 len reads,
//      LDS broadcast), running (bestLen, a0, a1) via cndmask.
//   3. GIoU for positives, shfl wave reduce, partial[bid] written
//      unconditionally every call (no memset, no atomics, no cross-call state).
__global__ __launch_bounds__(256) void fcos_main_kernel(
    const float* __restrict__ reg,      // (B, A_TOT, 2)
    const float* __restrict__ ann,      // (B, G, 3)
    float2* __restrict__ partial)       // (B*NBLK) {lossSum, cntSum}
{
    const int bid  = blockIdx.x;
    const int b    = bid / NBLK;
    const int blk  = bid % NBLK;
    const int t    = threadIdx.x;
    const int lane = t & 63;
    const int wid  = t >> 6;

    __shared__ __align__(16) float2 s_cpair[G + 2];
    __shared__ __align__(8)  float  s_clen[G + 2];
    __shared__ int   s_wcnt[4];
    __shared__ float s_wl[4], s_wc[4];

    // ---- level of this block (boundaries are multiples of 256; uniform) ----
    const int aidx0 = blk * 256;
    int lvl, off;
    if (aidx0 < 16384)      { lvl = 0; off = 0; }
    else if (aidx0 < 24576) { lvl = 1; off = 16384; }
    else if (aidx0 < 28672) { lvl = 2; off = 24576; }
    else if (aidx0 < 30720) { lvl = 3; off = 28672; }
    else if (aidx0 < 31744) { lvl = 4; off = 30720; }
    else                    { lvl = 5; off = 31744; }

    const float lo  = c_LO[lvl];
    const float hi  = c_HI[lvl];
    const float xlo = lo - 0.01f;
    const float xhi = 2.0f * hi + 0.01f;   // inf stays inf

    // ---- candidacy test + compaction (original order preserved) ----
    const float a0in = ann[(b * G + t) * 3 + 0];
    const float a1in = ann[(b * G + t) * 3 + 1];
    const float len  = a1in - a0in;
    const bool cand  = (len >= xlo) && (len < xhi);

    const unsigned long long vote = __ballot(cand);
    const int lanePos = __popcll(vote & ((1ull << lane) - 1ull));
    if (lane == 0) s_wcnt[wid] = __popcll(vote);
    __syncthreads();

    int base = 0, ncand = 0;
#pragma unroll
    for (int w = 0; w < 4; ++w) {
        const int c = s_wcnt[w];
        ncand += c;
        if (w < wid) base += c;
    }
    if (cand) {
        const int posi = base + lanePos;
        s_cpair[posi] = make_float2(a0in, a1in);
        s_clen[posi]  = len;
    }
    if (t == 0) {  // dummy pad for odd ncand: can never match (l < 0 always)
        s_cpair[ncand] = make_float2(3.0e30f, -3.0e30f);
        s_clen[ncand]  = 3.0e30f;
    }
    __syncthreads();

    // ---- branchless stable-min scan, 2 candidates per iteration ----
    const int   aidx = aidx0 + t;
    const float p    = (float)(aidx - off) * (float)(1 << lvl);  // exact

    float bestLen = 1.0e30f;
    float bA0 = 0.f, bA1 = 0.f;
    const int n2 = (ncand + 1) >> 1;
    const float4* pr4 = reinterpret_cast<const float4*>(s_cpair);
    const float2* ln2 = reinterpret_cast<const float2*>(s_clen);
#pragma unroll 4
    for (int j = 0; j < n2; ++j) {
        const float4 v  = pr4[j];
        const float2 l2 = ln2[j];
        const float la = p - v.x, ra = v.y - p;
        const float ma = fmaxf(la, ra);
        if ((fminf(la, ra) >= 0.f) & (ma >= lo) & (ma < hi) & (l2.x < bestLen)) {
            bestLen = l2.x; bA0 = v.x; bA1 = v.y;
        }
        const float lb = p - v.z, rb = v.w - p;
        const float mb = fmaxf(lb, rb);
        if ((fminf(lb, rb) >= 0.f) & (mb >= lo) & (mb < hi) & (l2.y < bestLen)) {
            bestLen = l2.y; bA0 = v.z; bA1 = v.w;
        }
    }

    // ---- GIoU for positives ----
    float loss = 0.f, cnt = 0.f;
    if (bestLen < 1.0e30f) {
        const float scale = 1.0f / (float)(1 << lvl);   // exact pow2
        const float a0 = bA0 * scale;
        const float a1 = bA1 * scale;
        const float2 rv = reinterpret_cast<const float2*>(reg)[b * A_TOT + aidx];
        const float inter = fmaxf(fminf(a1, rv.y) - fmaxf(a0, rv.x), 0.f);
        const float uni   = (a1 - a0) + (rv.y - rv.x) - inter;
        const float enc   = fmaxf(a1, rv.y) - fminf(a0, rv.x);
        const float iou   = inter / (uni + 1e-7f);
        const float giou  = iou - (enc - uni) / (enc + 1e-7f);
        loss = 1.0f - giou;
        cnt  = 1.0f;
    }

    // ---- wave reduce + block partial ----
#pragma unroll
    for (int m = 32; m; m >>= 1) { loss += __shfl_xor(loss, m); cnt += __shfl_xor(cnt, m); }
    if (lane == 0) { s_wl[wid] = loss; s_wc[wid] = cnt; }
    __syncthreads();
    if (t == 0) {
        const float L = s_wl[0] + s_wl[1] + s_wl[2] + s_wl[3];
        const float C = s_wc[0] + s_wc[1] + s_wc[2] + s_wc[3];
        partial[bid] = make_float2(L, C);
    }
}

// Finalize: 8 blocks x 1 wave, fixed summation order -> bit-deterministic.
__global__ __launch_bounds__(64) void finalize_kernel(
    const float2* __restrict__ partial, float* __restrict__ out)
{
    const int b = blockIdx.x;
    const int t = threadIdx.x;   // 64
    float L = 0.f, C = 0.f;
    for (int i = t; i < NBLK; i += 64) {
        const float2 v = partial[b * NBLK + i];
        L += v.x; C += v.y;
    }
#pragma unroll
    for (int m = 32; m; m >>= 1) { L += __shfl_xor(L, m); C += __shfl_xor(C, m); }
    if (t == 0) out[b] = L / fmaxf(C, 1.0f);
}

extern "C" void kernel_launch(void* const* d_in, const int* in_sizes, int n_in,
                              void* d_out, int out_size, void* d_ws, size_t ws_size,
                              hipStream_t stream) {
    const float* reg = (const float*)d_in[0];   // (B, A, 2)
    const float* ann = (const float*)d_in[1];   // (B, G, 3)
    float* out = (float*)d_out;                 // (B,)

    float2* partial = (float2*)d_ws;            // B*NBLK float2, fully rewritten each call

    fcos_main_kernel<<<BATCH * NBLK, 256, 0, stream>>>(reg, ann, partial);
    finalize_kernel<<<BATCH, 64, 0, stream>>>(partial, out);
}